// Round 1
// baseline (511.317 us; speedup 1.0000x reference)
//
#include <hip/hip_runtime.h>

#define N_NODES 4096
#define F_UAV 64
#define NOBS 262400
#define GCN_FLAT (N_NODES * F_UAV)   // 262144
#define HDIM 1024
#define N_ACT 64
#define N_EDGES 65536

// ---- workspace layout (float offsets) ----
#define OFF_X     0                        // 262400
#define OFF_H     262400                   // 262144
#define OFF_DINV  (OFF_H + GCN_FLAT)       // 4096
#define OFF_DEG   (OFF_DINV + N_NODES)     // 4096 (int)
#define OFF_P1    (OFF_DEG + N_NODES)      // 1025*1024
#define OFF_Y1    (OFF_P1 + 1025*1024)     // 1024
#define OFF_P2    (OFF_Y1 + HDIM)          // 64*1024
#define OFF_Y2    (OFF_P2 + 64*1024)       // 1024

// h = node_x @ gcn_w   (4096x64 @ 64x64)
__global__ __launch_bounds__(256) void k_gcn_h(const float* __restrict__ nx,
                                               const float* __restrict__ w,
                                               float* __restrict__ h) {
    __shared__ float sw[F_UAV * F_UAV];
    int tid = threadIdx.x;
    for (int i = tid; i < F_UAV * F_UAV; i += 256) sw[i] = w[i];
    __syncthreads();
    int i = blockIdx.x * 4 + (tid >> 6);
    int j = tid & 63;
    const float* row = nx + i * F_UAV;
    float acc = 0.f;
#pragma unroll
    for (int k = 0; k < F_UAV; ++k) acc += row[k] * sw[k * F_UAV + j];
    h[i * F_UAV + j] = acc;
}

__global__ void k_deg_zero(int* deg) {
    int i = blockIdx.x * 256 + threadIdx.x;
    if (i < N_NODES) deg[i] = 0;
}

__global__ void k_deg_count(const int* __restrict__ dst, int* deg) {
    int e = blockIdx.x * 256 + threadIdx.x;
    if (e < N_EDGES) atomicAdd(&deg[dst[e]], 1);
}

__global__ void k_dinv(const int* __restrict__ deg, float* __restrict__ dinv) {
    int i = blockIdx.x * 256 + threadIdx.x;
    if (i < N_NODES) dinv[i] = rsqrtf((float)(deg[i] + 1));  // +1 self-loop
}

// x[0:262144] = h*dinv^2 + gcn_b (self-loop term), x[262144:262400] = obs tail
__global__ void k_x_init(const float* __restrict__ h, const float* __restrict__ dinv,
                         const float* __restrict__ gb, const float* __restrict__ obs,
                         float* __restrict__ x) {
    int i = blockIdx.x * 256 + threadIdx.x;
    if (i < GCN_FLAT) {
        int node = i >> 6;
        float d = dinv[node];
        x[i] = h[i] * d * d + gb[i & 63];
    } else if (i < NOBS) {
        x[i] = obs[i];
    }
}

// one wave per edge, lane = feature
__global__ __launch_bounds__(256) void k_scatter(const int* __restrict__ src,
                                                 const int* __restrict__ dst,
                                                 const float* __restrict__ h,
                                                 const float* __restrict__ dinv,
                                                 float* __restrict__ x) {
    int t = blockIdx.x * 256 + threadIdx.x;
    int e = t >> 6;
    int j = t & 63;
    if (e < N_EDGES) {
        int s = dst ? src[e] : 0;
        int d = dst[e];
        float nrm = dinv[s] * dinv[d];
        atomicAdd(&x[d * 64 + j], h[s * 64 + j] * nrm);
    }
}

// partial mat-vec: y_part[block][j] = sum over this block's RPB rows of x[k]*W[k][j]
// W is [K][1024] row-major; 256 threads, thread t owns columns 4t..4t+3 (float4).
template <int RPB>
__global__ __launch_bounds__(256) void k_matvec_part(const float* __restrict__ x,
                                                     const float* __restrict__ W,
                                                     float* __restrict__ part) {
    __shared__ float sx[RPB];
    int tid = threadIdx.x;
    int k0 = blockIdx.x * RPB;
    for (int i = tid; i < RPB; i += 256) sx[i] = x[k0 + i];
    __syncthreads();
    float4 acc = {0.f, 0.f, 0.f, 0.f};
    const float4* Wr = ((const float4*)W) + (size_t)k0 * (HDIM / 4) + tid;
#pragma unroll 4
    for (int k = 0; k < RPB; ++k) {
        float xv = sx[k];
        float4 w = Wr[(size_t)k * (HDIM / 4)];
        acc.x += xv * w.x;
        acc.y += xv * w.y;
        acc.z += xv * w.z;
        acc.w += xv * w.w;
    }
    ((float4*)(part + (size_t)blockIdx.x * HDIM))[tid] = acc;
}

// y[j] = (relu?) (b[j] + sum_c part[c][j]);  grid 4 x 256
__global__ void k_reduce(const float* __restrict__ part, const float* __restrict__ b,
                         float* __restrict__ y, int nparts, int do_relu) {
    int j = blockIdx.x * 256 + threadIdx.x;
    if (j >= HDIM) return;
    float acc = b[j];
    for (int c = 0; c < nparts; ++c) acc += part[(size_t)c * HDIM + j];
    if (do_relu) acc = fmaxf(acc, 0.f);
    y[j] = acc;
}

// value/advantage heads + dueling combine. single block, 256 threads.
__global__ __launch_bounds__(256) void k_heads(const float* __restrict__ y2,
                                               const float* __restrict__ wv,
                                               const float* __restrict__ bv,
                                               const float* __restrict__ wa,
                                               const float* __restrict__ ba,
                                               float* __restrict__ out) {
    __shared__ float s_adv[4][64];
    __shared__ float s_pv[256];
    int t = threadIdx.x;
    int a = t & 63, g = t >> 6;
    float pa = 0.f, pv = 0.f;
    for (int kk = 0; kk < 256; ++kk) {
        int k = g * 256 + kk;
        pa += y2[k] * wa[k * 64 + a];
    }
    for (int k = t; k < HDIM; k += 256) pv += y2[k] * wv[k];
    s_adv[g][a] = pa;
    s_pv[t] = pv;
    __syncthreads();
    if (t < 64) {
        float adv = ba[a] + s_adv[0][a] + s_adv[1][a] + s_adv[2][a] + s_adv[3][a];
        float v = s_pv[a] + s_pv[a + 64] + s_pv[a + 128] + s_pv[a + 192];
        for (int off = 32; off; off >>= 1) v += __shfl_xor(v, off);
        float m = adv;
        for (int off = 32; off; off >>= 1) m += __shfl_xor(m, off);
        m *= (1.f / 64.f);
        out[a] = (v + bv[0]) + adv - m;
    }
}

extern "C" void kernel_launch(void* const* d_in, const int* in_sizes, int n_in,
                              void* d_out, int out_size, void* d_ws, size_t ws_size,
                              hipStream_t stream) {
    const float* node_x   = (const float*)d_in[0];
    const float* flat_obs = (const float*)d_in[1];
    const float* gcn_w    = (const float*)d_in[2];
    const float* gcn_b    = (const float*)d_in[3];
    const float* w1       = (const float*)d_in[4];
    const float* b1       = (const float*)d_in[5];
    const float* w2       = (const float*)d_in[6];
    const float* b2       = (const float*)d_in[7];
    const float* wv       = (const float*)d_in[8];
    const float* bv       = (const float*)d_in[9];
    const float* wa       = (const float*)d_in[10];
    const float* ba       = (const float*)d_in[11];
    const int*   ei       = (const int*)d_in[12];   // jax x64 disabled -> int32
    const int* src = ei;
    const int* dst = ei + N_EDGES;

    float* ws   = (float*)d_ws;
    float* x    = ws + OFF_X;
    float* h    = ws + OFF_H;
    float* dinv = ws + OFF_DINV;
    int*   deg  = (int*)(ws + OFF_DEG);
    float* p1   = ws + OFF_P1;
    float* y1   = ws + OFF_Y1;
    float* p2   = ws + OFF_P2;
    float* y2   = ws + OFF_Y2;
    float* out  = (float*)d_out;

    k_gcn_h<<<N_NODES / 4, 256, 0, stream>>>(node_x, gcn_w, h);
    k_deg_zero<<<(N_NODES + 255) / 256, 256, 0, stream>>>(deg);
    k_deg_count<<<(N_EDGES + 255) / 256, 256, 0, stream>>>(dst, deg);
    k_dinv<<<(N_NODES + 255) / 256, 256, 0, stream>>>(deg, dinv);
    k_x_init<<<(NOBS + 255) / 256, 256, 0, stream>>>(h, dinv, gcn_b, flat_obs, x);
    k_scatter<<<(N_EDGES * 64) / 256, 256, 0, stream>>>(src, dst, h, dinv, x);

    // y1 = relu(x @ w1 + b1): 1025 blocks x 256 rows
    k_matvec_part<256><<<1025, 256, 0, stream>>>(x, w1, p1);
    k_reduce<<<4, 256, 0, stream>>>(p1, b1, y1, 1025, 1);

    // y2 = relu(y1 @ w2 + b2): 64 blocks x 16 rows
    k_matvec_part<16><<<64, 256, 0, stream>>>(y1, w2, p2);
    k_reduce<<<4, 256, 0, stream>>>(p2, b2, y2, 64, 1);

    k_heads<<<1, 256, 0, stream>>>(y2, wv, bv, wa, ba, out);
}